// Round 5
// baseline (582.361 us; speedup 1.0000x reference)
//
#include <hip/hip_runtime.h>

#define NEG_SLOPE 0.2f

__device__ __forceinline__ float lrelu(float x) { return x > 0.0f ? x : NEG_SLOPE * x; }

__device__ __forceinline__ float bcast(float v, int srcLane) {
  return __int_as_float(__builtin_amdgcn_readlane(__float_as_int(v), srcLane));
}

// pack two floats as bf16 (RNE) into one uint: low16 = a, high16 = b
__device__ __forceinline__ unsigned pack_bf16(float a, float b) {
  unsigned ua = __float_as_uint(a), ub = __float_as_uint(b);
  ua += 0x7fffu + ((ua >> 16) & 1u);
  ub += 0x7fffu + ((ub >> 16) & 1u);
  return (ua >> 16) | (ub & 0xffff0000u);
}
__device__ __forceinline__ float bf16lo(unsigned z) { return __uint_as_float(z << 16); }
__device__ __forceinline__ float bf16hi(unsigned z) { return __uint_as_float(z & 0xffff0000u); }

// quantize ae to u8: q = clamp(round(ae*32)+128, 0, 255)
__device__ __forceinline__ unsigned quant8(float a) {
  int q = (int)rintf(a * 32.0f) + 128;
  q = q < 0 ? 0 : (q > 255 ? 255 : q);
  return (unsigned)q;
}
__device__ __forceinline__ float dequant8(unsigned q) {
  return ((int)q - 128) * (1.0f / 32.0f);
}

// ---------------------------------------------------------------------------
// K0: fold all small weights.
// ---------------------------------------------------------------------------
__global__ void k0_setup(const float* __restrict__ W, const float* __restrict__ proj_W,
                         const float* __restrict__ att_src, const float* __restrict__ att_dst,
                         const float* __restrict__ lin_edge_W, const float* __restrict__ att_edge,
                         const float* __restrict__ bias, const float* __restrict__ proj_b,
                         float* __restrict__ Wz, float* __restrict__ Ws, float* __restrict__ Wd,
                         float* __restrict__ M, float* __restrict__ cproj) {
  int t = blockIdx.x * blockDim.x + threadIdx.x;
  if (t < 16384) {
    int d = t >> 7, o = t & 127;
    int h = o >> 5, jj = o & 31;
    float s = 0.f;
    #pragma unroll
    for (int c = 0; c < 32; ++c)
      s += W[d * 128 + h * 32 + c] * proj_W[(h * 32 + c) * 32 + jj];
    Wz[d * 128 + o] = s;
  } else if (t < 16384 + 512) {
    int idx = t - 16384; int d = idx >> 2, h = idx & 3;
    float s = 0.f;
    #pragma unroll
    for (int c = 0; c < 32; ++c) s += W[d * 128 + h * 32 + c] * att_src[h * 32 + c];
    Ws[d * 4 + h] = s;
  } else if (t < 16384 + 1024) {
    int idx = t - 16384 - 512; int d = idx >> 2, h = idx & 3;
    float s = 0.f;
    #pragma unroll
    for (int c = 0; c < 32; ++c) s += W[d * 128 + h * 32 + c] * att_dst[h * 32 + c];
    Wd[d * 4 + h] = s;
  } else if (t < 16384 + 1024 + 128) {
    int idx = t - 16384 - 1024; int d = idx >> 2, h = idx & 3;
    float s = 0.f;
    #pragma unroll
    for (int c = 0; c < 32; ++c) s += lin_edge_W[d * 128 + h * 32 + c] * att_edge[h * 32 + c];
    M[d * 4 + h] = s;
  } else if (t < 16384 + 1024 + 128 + 32) {
    int jj = t - 16384 - 1024 - 128;
    float s = proj_b[jj];
    #pragma unroll
    for (int k = 0; k < 128; ++k) s += bias[k] * proj_W[k * 32 + jj];
    cproj[jj] = s;
  }
}

// ---------------------------------------------------------------------------
// K1: in-degree count + per-edge rank
// ---------------------------------------------------------------------------
__global__ void k1_count(const int* __restrict__ dst, int E, int* __restrict__ deg,
                         int* __restrict__ rank) {
  int i = blockIdx.x * blockDim.x + threadIdx.x;
  if (i < E) rank[i] = atomicAdd(&deg[dst[i]], 1);
}

// ---------------------------------------------------------------------------
// K2: single-block exclusive prefix scan -> offsets[N+1]; int4 per thread
// ---------------------------------------------------------------------------
__global__ void k2_scan(const int* __restrict__ deg, int n, int* __restrict__ offsets) {
  __shared__ int shw[16];
  __shared__ int shtot;
  int tid = threadIdx.x;
  int lane = tid & 63, wid = tid >> 6;
  int running = 0;
  for (int base = 0; base < n; base += 4096) {
    int i = base + tid * 4;
    int4 v = make_int4(0, 0, 0, 0);
    if (i + 3 < n) v = *(const int4*)&deg[i];
    else {
      if (i < n) v.x = deg[i];
      if (i + 1 < n) v.y = deg[i + 1];
      if (i + 2 < n) v.z = deg[i + 2];
      if (i + 3 < n) v.w = deg[i + 3];
    }
    int tsum = v.x + v.y + v.z + v.w;
    int inc = tsum;
    #pragma unroll
    for (int s = 1; s < 64; s <<= 1) {
      int t = __shfl_up(inc, s);
      if (lane >= s) inc += t;
    }
    if (lane == 63) shw[wid] = inc;
    __syncthreads();
    if (wid == 0) {
      int w = (lane < 16) ? shw[lane] : 0;
      int winc = w;
      #pragma unroll
      for (int s = 1; s < 16; s <<= 1) {
        int t = __shfl_up(winc, s);
        if (lane >= s) winc += t;
      }
      if (lane < 16) shw[lane] = winc - w;
      if (lane == 15) shtot = winc;
    }
    __syncthreads();
    int excl = running + shw[wid] + inc - tsum;
    if (i < n)     offsets[i + 1] = excl + v.x;
    if (i + 1 < n) offsets[i + 2] = excl + v.x + v.y;
    if (i + 2 < n) offsets[i + 3] = excl + v.x + v.y + v.z;
    if (i + 3 < n) offsets[i + 4] = excl + tsum;
    running += shtot;
    __syncthreads();
  }
  if (tid == 0) offsets[0] = 0;
}

// ---------------------------------------------------------------------------
// K3: Zp (bf16-packed x@Wz) | a_src | a_dst
// ---------------------------------------------------------------------------
__global__ __launch_bounds__(256) void k3_gemm(
    const float* __restrict__ x, const float* __restrict__ Wz,
    const float* __restrict__ Ws, const float* __restrict__ Wd,
    int n, unsigned* __restrict__ Zp, float* __restrict__ a_src, float* __restrict__ a_dst) {
  __shared__ float2 Wl[128 * 64];  // 64 KB
  int tid = threadIdx.x;
  for (int idx = tid; idx < 128 * 64; idx += 256) {
    int k = idx >> 6, l = idx & 63;
    Wl[idx] = make_float2(Wz[k * 128 + l], Wz[k * 128 + 64 + l]);
  }
  __syncthreads();
  int lane = tid & 63, wid = tid >> 6;
  float ws0[4], ws1[4], wd0[4], wd1[4];
  #pragma unroll
  for (int h = 0; h < 4; ++h) {
    ws0[h] = Ws[lane * 4 + h];  ws1[h] = Ws[(64 + lane) * 4 + h];
    wd0[h] = Wd[lane * 4 + h];  wd1[h] = Wd[(64 + lane) * 4 + h];
  }
  int gw = blockIdx.x * 4 + wid;
  int nw = gridDim.x * 4;
  for (int base = gw * 4; base < n; base += nw * 4) {
    float xa[4], xb[4];
    #pragma unroll
    for (int u = 0; u < 4; ++u) {
      int node = base + u;
      xa[u] = (node < n) ? x[node * 128 + lane] : 0.0f;
      xb[u] = (node < n) ? x[node * 128 + 64 + lane] : 0.0f;
    }
    float acc0[4] = {0.f, 0.f, 0.f, 0.f}, acc1[4] = {0.f, 0.f, 0.f, 0.f};
    #pragma unroll 16
    for (int k = 0; k < 64; ++k) {
      float2 w = Wl[k * 64 + lane];
      #pragma unroll
      for (int u = 0; u < 4; ++u) {
        float xv = bcast(xa[u], k);
        acc0[u] += xv * w.x; acc1[u] += xv * w.y;
      }
    }
    #pragma unroll 16
    for (int k = 0; k < 64; ++k) {
      float2 w = Wl[(64 + k) * 64 + lane];
      #pragma unroll
      for (int u = 0; u < 4; ++u) {
        float xv = bcast(xb[u], k);
        acc0[u] += xv * w.x; acc1[u] += xv * w.y;
      }
    }
    #pragma unroll
    for (int u = 0; u < 4; ++u) {
      int node = base + u;
      if (node >= n) break;
      Zp[(size_t)node * 64 + lane] = pack_bf16(acc0[u], acc1[u]);
      float ps[4], pd[4];
      #pragma unroll
      for (int h = 0; h < 4; ++h) {
        ps[h] = xa[u] * ws0[h] + xb[u] * ws1[h];
        pd[h] = xa[u] * wd0[h] + xb[u] * wd1[h];
      }
      #pragma unroll
      for (int m = 1; m < 64; m <<= 1) {
        #pragma unroll
        for (int h = 0; h < 4; ++h) {
          ps[h] += __shfl_xor(ps[h], m);
          pd[h] += __shfl_xor(pd[h], m);
        }
      }
      if (lane == 0) {
        *(float4*)&a_src[node * 4] = make_float4(ps[0], ps[1], ps[2], ps[3]);
        *(float4*)&a_dst[node * 4] = make_float4(pd[0], pd[1], pd[2], pd[3]);
      }
    }
  }
}

// ---------------------------------------------------------------------------
// K4 (fused): stream ea -> ae; gather a_src[s], a_dst[d]; compute exp-weights;
// scatter ONE 16B CSR entry {src, w01.bf16, w23.bf16, ae.u8x4} directly.
// ---------------------------------------------------------------------------
__global__ __launch_bounds__(256, 4) void k4_edge(
    const int* __restrict__ ei, int E, const float4* __restrict__ ea4,
    const float* __restrict__ Mg,
    const float* __restrict__ a_src, const float* __restrict__ a_dst,
    const int* __restrict__ rank, const int* __restrict__ offsets,
    uint4* __restrict__ csr) {
  __shared__ float4 s_ea[256 * 9];  // 8 data + 1 pad per edge = 36 KB
  __shared__ float4 Msh[32];
  int t = threadIdx.x;
  if (t < 32) Msh[t] = ((const float4*)Mg)[t];
  int B0 = blockIdx.x * 256;
  #pragma unroll
  for (int k = 0; k < 8; ++k) {
    int f = k * 256 + t;
    int e = B0 + (f >> 3);
    float4 v = (e < E) ? ea4[(size_t)B0 * 8 + f] : make_float4(0.f, 0.f, 0.f, 0.f);
    s_ea[(f >> 3) * 9 + (f & 7)] = v;
  }
  __syncthreads();
  int e = B0 + t;
  if (e >= E) return;
  // start the index + gather chain early
  int s = ei[e], d = ei[E + e];
  float4 as = *(const float4*)&a_src[(size_t)s * 4];
  float4 ad = *(const float4*)&a_dst[(size_t)d * 4];
  int slot = offsets[d] + rank[e];
  float ae0 = 0.f, ae1 = 0.f, ae2 = 0.f, ae3 = 0.f;
  #pragma unroll
  for (int j = 0; j < 8; ++j) {
    float4 v = s_ea[t * 9 + j];
    float4 m0 = Msh[j * 4 + 0], m1 = Msh[j * 4 + 1], m2 = Msh[j * 4 + 2], m3 = Msh[j * 4 + 3];
    ae0 += v.x * m0.x + v.y * m1.x + v.z * m2.x + v.w * m3.x;
    ae1 += v.x * m0.y + v.y * m1.y + v.z * m2.y + v.w * m3.y;
    ae2 += v.x * m0.z + v.y * m1.z + v.z * m2.z + v.w * m3.z;
    ae3 += v.x * m0.w + v.y * m1.w + v.z * m2.w + v.w * m3.w;
  }
  float w0 = __expf(lrelu(ae0 + as.x + ad.x));
  float w1 = __expf(lrelu(ae1 + as.y + ad.y));
  float w2 = __expf(lrelu(ae2 + as.z + ad.z));
  float w3 = __expf(lrelu(ae3 + as.w + ad.w));
  unsigned aeq = quant8(ae0) | (quant8(ae1) << 8) | (quant8(ae2) << 16) | (quant8(ae3) << 24);
  csr[slot] = make_uint4((unsigned)s, pack_bf16(w0, w1), pack_bf16(w2, w3), aeq);
}

// ---------------------------------------------------------------------------
// K5: wave-per-node. Phase A: coalesced 16B CSR stream (no gathers, no exp) ->
// dsum/aeSum partials + LDS stash. Phase B: Zp row gather + 2 FMA/edge.
// ---------------------------------------------------------------------------
__global__ __launch_bounds__(256) void k5_agg(
    const int* __restrict__ offsets, const uint4* __restrict__ csr,
    const unsigned* __restrict__ Zp,
    const float* __restrict__ a_src, const float* __restrict__ a_dst,
    const float* __restrict__ cproj, int n, float* __restrict__ out) {
  __shared__ float4 s_w[4][64];
  __shared__ int    s_s[4][64];
  int tid = threadIdx.x;
  int lane = tid & 63, wid = tid >> 6;
  int gw = blockIdx.x * 4 + wid, nw = gridDim.x * 4;
  int h0 = lane >> 5, j = lane & 31;
  float cp = cproj[j];
  const float* wbase = (const float*)&s_w[wid][0];
  for (int node = gw; node < n; node += nw) {
    int off0 = offsets[node], off1 = offsets[node + 1];
    int dg = off1 - off0;
    float dsx = 0.f, dsy = 0.f, dsz = 0.f, dsw = 0.f;
    float aex = 0.f, aey = 0.f, aez = 0.f, aew = 0.f;
    float agg0 = 0.f, agg1 = 0.f;
    for (int base = off0; base < off1; base += 64) {
      int rem = off1 - base; if (rem > 64) rem = 64;
      // ---- phase A: coalesced CSR read ----
      if (lane < rem) {
        uint4 ent = csr[(size_t)(base + lane)];
        int s = (int)ent.x;
        float w0 = bf16lo(ent.y), w1 = bf16hi(ent.y);
        float w2 = bf16lo(ent.z), w3 = bf16hi(ent.z);
        dsx += w0; dsy += w1; dsz += w2; dsw += w3;
        aex += dequant8(ent.w & 255u);
        aey += dequant8((ent.w >> 8) & 255u);
        aez += dequant8((ent.w >> 16) & 255u);
        aew += dequant8(ent.w >> 24);
        s_w[wid][lane] = make_float4(w0, w2, w1, w3);  // pair (h, h+2) adjacent
        s_s[wid][lane] = s;
      }
      // ---- phase B ----
      int jj = 0;
      for (; jj + 4 <= rem; jj += 4) {
        int s0 = s_s[wid][jj], s1 = s_s[wid][jj + 1];
        int s2 = s_s[wid][jj + 2], s3 = s_s[wid][jj + 3];
        unsigned z0 = Zp[(size_t)s0 * 64 + lane];
        unsigned z1 = Zp[(size_t)s1 * 64 + lane];
        unsigned z2 = Zp[(size_t)s2 * 64 + lane];
        unsigned z3 = Zp[(size_t)s3 * 64 + lane];
        float2 w0 = *(const float2*)(wbase + (jj    ) * 4 + 2 * h0);
        float2 w1 = *(const float2*)(wbase + (jj + 1) * 4 + 2 * h0);
        float2 w2 = *(const float2*)(wbase + (jj + 2) * 4 + 2 * h0);
        float2 w3 = *(const float2*)(wbase + (jj + 3) * 4 + 2 * h0);
        agg0 += w0.x * bf16lo(z0) + w1.x * bf16lo(z1) + w2.x * bf16lo(z2) + w3.x * bf16lo(z3);
        agg1 += w0.y * bf16hi(z0) + w1.y * bf16hi(z1) + w2.y * bf16hi(z2) + w3.y * bf16hi(z3);
      }
      for (; jj < rem; ++jj) {
        int s0 = s_s[wid][jj];
        unsigned z0 = Zp[(size_t)s0 * 64 + lane];
        float2 w0 = *(const float2*)(wbase + jj * 4 + 2 * h0);
        agg0 += w0.x * bf16lo(z0);
        agg1 += w0.y * bf16hi(z0);
      }
    }
    // ---- wave reduction of dsum / aeSum partials ----
    #pragma unroll
    for (int m = 1; m < 64; m <<= 1) {
      dsx += __shfl_xor(dsx, m); dsy += __shfl_xor(dsy, m);
      dsz += __shfl_xor(dsz, m); dsw += __shfl_xor(dsw, m);
      aex += __shfl_xor(aex, m); aey += __shfl_xor(aey, m);
      aez += __shfl_xor(aez, m); aew += __shfl_xor(aew, m);
    }
    // ---- self-loop (attr = mean of incoming -> aeSum/deg by linearity) ----
    float invd = 1.0f / (float)(dg > 0 ? dg : 1);
    float4 asn = *(const float4*)&a_src[node * 4];
    float4 ad  = *(const float4*)&a_dst[node * 4];
    float w0 = __expf(lrelu(asn.x + ad.x + aex * invd));
    float w1 = __expf(lrelu(asn.y + ad.y + aey * invd));
    float w2 = __expf(lrelu(asn.z + ad.z + aez * invd));
    float w3 = __expf(lrelu(asn.w + ad.w + aew * invd));
    dsx += w0; dsy += w1; dsz += w2; dsw += w3;
    unsigned zpn = Zp[(size_t)node * 64 + lane];
    float sw0 = h0 ? w1 : w0, sw1 = h0 ? w3 : w2;
    agg0 += sw0 * bf16lo(zpn);
    agg1 += sw1 * bf16hi(zpn);
    float d0 = h0 ? dsy : dsx, d1 = h0 ? dsw : dsz;
    float tt = agg0 / (d0 + 1e-16f) + agg1 / (d1 + 1e-16f);
    tt += __shfl_xor(tt, 32);
    if (lane < 32) out[node * 32 + j] = tt + cp;
  }
}

// ---------------------------------------------------------------------------
extern "C" void kernel_launch(void* const* d_in, const int* in_sizes, int n_in,
                              void* d_out, int out_size, void* d_ws, size_t ws_size,
                              hipStream_t stream) {
  const float* x          = (const float*)d_in[0];
  const int*   ei         = (const int*)  d_in[1];
  const float* ea         = (const float*)d_in[2];
  const float* W          = (const float*)d_in[3];
  const float* att_src    = (const float*)d_in[4];
  const float* att_dst    = (const float*)d_in[5];
  const float* lin_edge_W = (const float*)d_in[6];
  const float* att_edge   = (const float*)d_in[7];
  const float* bias       = (const float*)d_in[8];
  const float* proj_W     = (const float*)d_in[9];
  const float* proj_b     = (const float*)d_in[10];
  float* out = (float*)d_out;
  int N = in_sizes[0] / 128;
  int E = in_sizes[1] / 2;

  char* p = (char*)d_ws;
  auto alloc = [&](size_t bytes) {
    char* r = p;
    p += (bytes + 255) & ~(size_t)255;
    return r;
  };
  unsigned* Zp     = (unsigned*)alloc((size_t)N * 64 * 4);
  float* a_src     = (float*)alloc((size_t)N * 4 * 4);
  float* a_dst     = (float*)alloc((size_t)N * 4 * 4);
  int*   deg       = (int*)  alloc((size_t)N * 4);
  int*   offsets   = (int*)  alloc((size_t)(N + 1) * 4);
  int*   rank      = (int*)  alloc((size_t)E * 4);
  uint4* csr       = (uint4*)alloc((size_t)E * 16);
  float* Wz        = (float*)alloc(128 * 128 * 4);
  float* Ws        = (float*)alloc(128 * 4 * 4);
  float* Wd        = (float*)alloc(128 * 4 * 4);
  float* M         = (float*)alloc(32 * 4 * 4);
  float* cproj     = (float*)alloc(32 * 4);

  hipMemsetAsync(deg, 0, (size_t)N * 4, stream);

  k0_setup<<<69, 256, 0, stream>>>(W, proj_W, att_src, att_dst, lin_edge_W, att_edge,
                                   bias, proj_b, Wz, Ws, Wd, M, cproj);
  k1_count<<<(E + 255) / 256, 256, 0, stream>>>(ei + E, E, deg, rank);
  k2_scan<<<1, 1024, 0, stream>>>(deg, N, offsets);
  k3_gemm<<<512, 256, 0, stream>>>(x, Wz, Ws, Wd, N, Zp, a_src, a_dst);
  k4_edge<<<(E + 255) / 256, 256, 0, stream>>>(ei, E, (const float4*)ea, M,
                                               a_src, a_dst, rank, offsets, csr);
  k5_agg<<<2048, 256, 0, stream>>>(offsets, csr, Zp, a_src, a_dst, cproj, N, out);
}